// Round 9
// baseline (1083.403 us; speedup 1.0000x reference)
//
#include <hip/hip_runtime.h>
#include <hip/hip_bf16.h>
#include <math.h>

typedef unsigned short ushort_t;
typedef __attribute__((ext_vector_type(8))) short short8;
typedef __attribute__((ext_vector_type(4))) float f32x4;
typedef __attribute__((ext_vector_type(4))) int int4v;
#define MFMA __builtin_amdgcn_mfma_f32_16x16x32_bf16

#define NPOS 262144
#define NSTEPS 5

// workspace byte offsets (guard page before state0 for wloc=-1 halo loads)
#define OB_S0   4096u
#define OB_S1   (OB_S0 + 33554432u)
#define OB_STG  (OB_S1 + 33554432u)       // 157696 B: [w1f|w2f|wtf|cbf|nh]
#define STG_W2  73728u
#define STG_WT  81920u
#define STG_CB  90112u
#define STG_NH  155648u
#define STG_SZ  157696u
#define OB_SWT  (OB_STG + STG_SZ)         // f32 [9][64] stem weights (permuted slots)
#define OB_SBP  (OB_SWT + 2304u)          // f32 [64] stem bias (permuted)
#define OB_PART (OB_SBP + 256u)           // f32 [5][8192] per-wave partials
#define DYN_LDS 157696u
// LESSON (R5-R8, unified VGPR/AGPR file on gfx950): CSV VGPR_Count = arch VGPRs only;
// MFMA accumulators (AGPRs) add on top. Waves/SIMD = 512 / (arch+acc). The pf=4 body
// needs ~200 total -> 2 waves/SIMD (20% occupancy) regardless of LDS size -- LDS was
// never the blocker. A 1024-thr block forces 16 waves/CU = 4 waves/SIMD = <=128 total;
// pf=4 spilled there (R5). Fix: pf=2 body (~100 total) + 1024-thr block.

// physical slot p = 32s + 8kg + 4u + r  ->  logical channel 32s + 16u + 4kg + r
static __device__ __forceinline__ int permP(int p) {
  return (p & 0x23) | ((p >> 1) & 0x0c) | ((p & 0x4) << 2);
}
static __device__ __forceinline__ ushort_t f2bf(float f) {
  __hip_bfloat16 h = __float2bfloat16(f);
  return *reinterpret_cast<ushort_t*>(&h);
}
static __device__ __forceinline__ float bf2f(ushort_t h) {
  return __uint_as_float(((unsigned)h) << 16);
}

// ---------------- prep: fragment-major bf16 weights/codebook + stem tables ----------------
__global__ void prep_kernel(const float* __restrict__ up1_w, const float* __restrict__ up2_w,
                            const float* __restrict__ tau_w, const float* __restrict__ cb,
                            const float* __restrict__ stem_w, const float* __restrict__ stem_b,
                            char* __restrict__ ws) {
  int id = blockIdx.x * 256 + threadIdx.x;
  ushort_t* stg = (ushort_t*)(ws + OB_STG);
  if (id < 36864) {                       // w1f: [tap][s][f][lane][j]
    int j = id & 7, lane = (id >> 3) & 63, f = (id >> 9) & 3, s = (id >> 11) & 1, tap = id >> 12;
    int col = lane & 15, kg = lane >> 4;
    stg[id] = f2bf(up1_w[((16 * f + col) * 64 + permP(32 * s + 8 * kg + j)) * 9 + tap]);
  } else if (id < 40960) {                // w2f: [s][f][lane][j]
    int jj = id - 36864;
    int j = jj & 7, lane = (jj >> 3) & 63, f = (jj >> 9) & 3, s = (jj >> 11) & 1;
    int col = lane & 15, kg = lane >> 4;
    stg[id] = f2bf(up2_w[(16 * f + col) * 64 + permP(32 * s + 8 * kg + j)]);
  } else if (id < 45056) {                // wtf
    int jj = id - 40960;
    int j = jj & 7, lane = (jj >> 3) & 63, f = (jj >> 9) & 3, s = (jj >> 11) & 1;
    int col = lane & 15, kg = lane >> 4;
    stg[id] = f2bf(tau_w[(16 * f + col) * 64 + permP(32 * s + 8 * kg + j)]);
  } else if (id < 77824) {                // cbf: [cf][s][lane][j]
    int jj = id - 45056;
    int j = jj & 7, lane = (jj >> 3) & 63, s = (jj >> 9) & 1, cf = jj >> 10;
    int col = lane & 15, kg = lane >> 4;
    stg[id] = f2bf(cb[(16 * cf + col) * 64 + permP(32 * s + 8 * kg + j)]);
  } else if (id < 78336) {                // nh = -0.5*|c|^2
    int k = id - 77824;
    float s = 0.f;
    for (int c = 0; c < 64; ++c) { float v = cb[k * 64 + c]; s += v * v; }
    ((float*)(ws + OB_STG + STG_NH))[k] = -0.5f * s;
  } else if (id < 78912) {                // stem weights [tap][slot]
    int jj = id - 78336; int tap = jj >> 6, slot = jj & 63;
    ((float*)(ws + OB_SWT))[jj] = stem_w[permP(slot) * 9 + tap];
  } else if (id < 78976) {                // stem bias [slot]
    int slot = id - 78912;
    ((float*)(ws + OB_SBP))[slot] = stem_b[permP(slot)];
  }
}

// ---------------- stem: conv3x3 1->64 + relu, thread-per-position ----------------
__global__ __launch_bounds__(256) void stem_kernel(const float* __restrict__ x,
      const char* __restrict__ wsro, ushort_t* __restrict__ state) {
  const float* swt = (const float*)(wsro + OB_SWT);
  const float* sbp = (const float*)(wsro + OB_SBP);
  int pos = blockIdx.x * 256 + threadIdx.x;
  int b = pos >> 14, hw = pos & 16383, h = hw >> 7, w = hw & 127;
  const float* xb = x + b * 16384;
  float xv[9];
  #pragma unroll
  for (int ky = 0; ky < 3; ++ky) {
    #pragma unroll
    for (int kx = 0; kx < 3; ++kx) {
      int hh = h + ky - 1, ww = w + kx - 1;
      bool ok = (hh >= 0) && (hh < 128) && (ww >= 0) && (ww < 128);
      xv[ky * 3 + kx] = ok ? xb[hh * 128 + ww] : 0.f;
    }
  }
  float acc[64];
  #pragma unroll
  for (int i = 0; i < 64; ++i) acc[i] = sbp[i];
  #pragma unroll
  for (int tap = 0; tap < 9; ++tap) {
    float xt = xv[tap];
    #pragma unroll
    for (int g = 0; g < 16; ++g) {
      f32x4 w4 = *(const f32x4*)(swt + tap * 64 + g * 4);
      #pragma unroll
      for (int j = 0; j < 4; ++j) acc[g * 4 + j] += xt * w4[j];
    }
  }
  ushort_t* op = state + (size_t)pos * 64;
  #pragma unroll
  for (int sg = 0; sg < 8; ++sg) {
    short8 o;
    #pragma unroll
    for (int j = 0; j < 8; ++j) o[j] = (short)f2bf(fmaxf(acc[sg * 8 + j], 0.f));
    *(short8*)(op + sg * 8) = o;
  }
}

// ---------------- fused step: 1024 thr (16 waves/CU forced), pf=2, full LDS staging ----------------
// Block = 16 waves; WU = 4 image rows (512 pos); wave owns 32 pos (2 pf) of one row.
// wave wv: row = row0 + (wv>>2), chunk = (wv&3)*32. 2 WUs per block.
__global__ __launch_bounds__(1024, 4) void step_kernel(const ushort_t* __restrict__ sin,
      ushort_t* __restrict__ sout, const char* __restrict__ wsro,
      const float* __restrict__ up1_b, const float* __restrict__ up2_b,
      const float* __restrict__ tau_b, float* __restrict__ partials) {
  extern __shared__ char smem[];
  int t = threadIdx.x, lane = t & 63, wv = t >> 6;
  int col = lane & 15, kg = lane >> 4;

  // stage all weights/codebook into LDS (linear copy, conflict-free)
  const char* src = wsro + OB_STG;
  #pragma unroll
  for (int it = 0; it < 10; ++it) {
    int c = it * 1024 + t;
    if (c < 9856) *(int4v*)(smem + c * 16) = *(const int4v*)(src + c * 16);
  }
  __syncthreads();

  for (int wi = 0; wi < 2; ++wi) {
    int wu = blockIdx.x + wi * 256;             // 512 WUs
    int lb = ((wu & 7) << 6) | (wu >> 3);       // XCD-chunked: XCD x owns images 2x,2x+1
    int b = lb >> 5;
    int row = (lb & 31) * 4 + (wv >> 2);
    int chunk = (wv & 3) * 32;
    const ushort_t* imgbase = sin + (size_t)b * 1048576u;

    // ---- up1: D = W1 . state^T (m=co, n=pos), A-frags from LDS ----
    f32x4 acc1[2][4] = {};                      // [pf][f]
    #pragma unroll
    for (int ky = 0; ky < 3; ++ky) {
      int h2 = row + ky - 1;
      if (h2 < 0 || h2 > 127) continue;         // wave-uniform
      const ushort_t* rptr = imgbase + h2 * 8192;
      #pragma unroll
      for (int kx = 0; kx < 3; ++kx) {
        short8 sbf[2][2];
        #pragma unroll
        for (int pf = 0; pf < 2; ++pf) {
          int wloc = chunk + 16 * pf + col + kx - 1;
          const ushort_t* pp = rptr + wloc * 64 + 8 * kg;
          sbf[pf][0] = *(const short8*)(pp);
          sbf[pf][1] = *(const short8*)(pp + 32);
          if ((kx == 0 && pf == 0) || (kx == 2 && pf == 1)) {
            if ((unsigned)wloc >= 128u) {
              short8 z8 = {};
              sbf[pf][0] = z8; sbf[pf][1] = z8;
            }
          }
        }
        int tap = ky * 3 + kx;
        #pragma unroll
        for (int s = 0; s < 2; ++s) {
          #pragma unroll
          for (int f = 0; f < 4; ++f) {
            short8 a = *(const short8*)(smem + ((tap * 2 + s) * 4 + f) * 1024 + lane * 16);
            #pragma unroll
            for (int pf = 0; pf < 2; ++pf)
              acc1[pf][f] = MFMA(a, sbf[pf][s], acc1[pf][f], 0, 0, 0);
          }
        }
      }
    }

    // ---- hidden = relu(D1+b1) packed to B-frag layout (slot identity) ----
    short8 hb[2][2];
    #pragma unroll
    for (int pf = 0; pf < 2; ++pf) {
      #pragma unroll
      for (int s = 0; s < 2; ++s) {
        short8 v;
        #pragma unroll
        for (int u = 0; u < 2; ++u) {
          int f = 2 * s + u;
          f32x4 b1 = *(const f32x4*)(up1_b + 16 * f + 4 * kg);
          #pragma unroll
          for (int r = 0; r < 4; ++r)
            v[4 * u + r] = (short)f2bf(fmaxf(acc1[pf][f][r] + b1[r], 0.f));
        }
        hb[pf][s] = v;
      }
    }

    // ---- up2/tau + gated z, pack zhat (weights from LDS) ----
    short8 zb[2][2];
    #pragma unroll
    for (int pf = 0; pf < 2; ++pf) {
      int wloc = chunk + 16 * pf + col;
      const ushort_t* cp = imgbase + row * 8192 + wloc * 64 + 8 * kg;
      short8 c0 = *(const short8*)(cp);
      short8 c1 = *(const short8*)(cp + 32);
      f32x4 d2[4] = {}, dt[4] = {};
      #pragma unroll
      for (int s = 0; s < 2; ++s) {
        short8 cs = s ? c1 : c0;
        #pragma unroll
        for (int f = 0; f < 4; ++f) {
          short8 wa2 = *(const short8*)(smem + STG_W2 + (s * 4 + f) * 1024 + lane * 16);
          short8 wat = *(const short8*)(smem + STG_WT + (s * 4 + f) * 1024 + lane * 16);
          d2[f] = MFMA(wa2, hb[pf][s], d2[f], 0, 0, 0);
          dt[f] = MFMA(wat, cs, dt[f], 0, 0, 0);
        }
      }
      #pragma unroll
      for (int s = 0; s < 2; ++s) {
        short8 cs = s ? c1 : c0;
        short8 zv;
        #pragma unroll
        for (int u = 0; u < 2; ++u) {
          int f = 2 * s + u;
          f32x4 b2 = *(const f32x4*)(up2_b + 16 * f + 4 * kg);
          f32x4 bt = *(const f32x4*)(tau_b + 16 * f + 4 * kg);
          #pragma unroll
          for (int r = 0; r < 4; ++r) {
            float sv = bf2f((ushort_t)cs[4 * u + r]);
            float xg = dt[f][r] + bt[r];
            float beta = __builtin_amdgcn_rcpf(1.f + __expf(-xg));
            float z = beta * sv + (1.f - beta) * (d2[f][r] + b2[r]);
            zv[4 * u + r] = (short)f2bf(z);
          }
        }
        zb[pf][s] = zv;
      }
    }

    // ---- VQ: argmax (z.c - |c|^2/2), codebook frags from LDS ----
    float bd[2] = {-3.0e38f, -3.0e38f};
    int bki[2] = {0, 0};
    #pragma unroll 2
    for (int cf = 0; cf < 32; ++cf) {
      short8 a0 = *(const short8*)(smem + STG_CB + (cf * 2 + 0) * 1024 + lane * 16);
      short8 a1 = *(const short8*)(smem + STG_CB + (cf * 2 + 1) * 1024 + lane * 16);
      f32x4 cinit = *(const f32x4*)(smem + STG_NH + (16 * cf + 4 * kg) * 4);
      #pragma unroll
      for (int pf = 0; pf < 2; ++pf) {
        f32x4 acc = cinit;
        acc = MFMA(a0, zb[pf][0], acc, 0, 0, 0);
        acc = MFMA(a1, zb[pf][1], acc, 0, 0, 0);
        #pragma unroll
        for (int r = 0; r < 4; ++r) {
          int code = 16 * cf + 4 * kg + r;
          if (acc[r] > bd[pf]) { bd[pf] = acc[r]; bki[pf] = code; }
        }
      }
    }

    // ---- cross-kg argmax, z_q gather from LDS codebook, store, loss ----
    float ls = 0.f;
    ushort_t* outbase = sout + (size_t)b * 1048576u + row * 8192;
    #pragma unroll
    for (int pf = 0; pf < 2; ++pf) {
      float d = bd[pf]; int k = bki[pf];
      #pragma unroll
      for (int off = 16; off <= 32; off <<= 1) {
        float od = __shfl_xor(d, off);
        int   ok = __shfl_xor(k, off);
        if (od > d || (od == d && ok < k)) { d = od; k = ok; }
      }
      int cbase = STG_CB + (k >> 4) * 2048 + (16 * kg + (k & 15)) * 16;
      short8 q0 = *(const short8*)(smem + cbase);
      short8 q1 = *(const short8*)(smem + cbase + 1024);
      ushort_t* op = outbase + (chunk + 16 * pf + col) * 64 + 8 * kg;
      *(short8*)(op) = q0;
      *(short8*)(op + 32) = q1;
      #pragma unroll
      for (int s = 0; s < 2; ++s) {
        short8 q = s ? q1 : q0;
        short8 zv = zb[pf][s];
        #pragma unroll
        for (int j = 0; j < 8; ++j) {
          float dd = bf2f((ushort_t)q[j]) - bf2f((ushort_t)zv[j]);
          ls += dd * dd;
        }
      }
    }
    #pragma unroll
    for (int off = 1; off < 64; off <<= 1) ls += __shfl_xor(ls, off);
    if (lane == 0) partials[wu * 16 + wv] = ls;   // per-wave partial, no LDS/barrier
  }
}

// ---------------- dec: 1x1 64->1 + sigmoid, coalesced; block 0 reduces loss ----------------
__global__ __launch_bounds__(256) void dec_kernel(const ushort_t* __restrict__ state,
      const float* __restrict__ dec_w, const float* __restrict__ dec_b,
      const float* __restrict__ part, float* __restrict__ out) {
  __shared__ float wsm[64];
  __shared__ float rs[256];
  int t = threadIdx.x;
  if (t < 64) wsm[t] = dec_w[permP(t)];
  __syncthreads();
  int wv = t >> 6, lane = t & 63;
  int pl = lane >> 3, sc = lane & 7;
  float b0 = dec_b[0];
  int base0 = blockIdx.x * 256;
  #pragma unroll
  for (int it = 0; it < 8; ++it) {
    int pos = base0 + it * 32 + wv * 8 + pl;
    short8 v = *(const short8*)(state + (size_t)pos * 64 + sc * 8);
    float d = 0.f;
    #pragma unroll
    for (int j = 0; j < 8; ++j) d += bf2f((ushort_t)v[j]) * wsm[sc * 8 + j];
    d += __shfl_xor(d, 1); d += __shfl_xor(d, 2); d += __shfl_xor(d, 4);
    if (sc == 0) out[pos] = __builtin_amdgcn_rcpf(1.f + __expf(-(d + b0)));
  }
  if (blockIdx.x == 0) {
    float v = 0.f;
    for (int i = t; i < 40960; i += 256) v += part[i];
    rs[t] = v;
    __syncthreads();
    for (int w = 128; w >= 1; w >>= 1) {
      if (t < w) rs[t] += rs[t + w];
      __syncthreads();
    }
    if (t == 0) out[NPOS] = rs[0] * 1.25f / (16777216.f * 5.f);
  }
}

extern "C" void kernel_launch(void* const* d_in, const int* in_sizes, int n_in,
                              void* d_out, int out_size, void* d_ws, size_t ws_size,
                              hipStream_t stream) {
  (void)in_sizes; (void)n_in; (void)out_size; (void)ws_size;
  const float* x      = (const float*)d_in[0];
  const float* stem_w = (const float*)d_in[1];
  const float* stem_b = (const float*)d_in[2];
  const float* up1_w  = (const float*)d_in[3];
  const float* up1_b  = (const float*)d_in[4];
  const float* up2_w  = (const float*)d_in[5];
  const float* up2_b  = (const float*)d_in[6];
  const float* tau_w  = (const float*)d_in[7];
  const float* tau_b  = (const float*)d_in[8];
  const float* cb     = (const float*)d_in[9];
  const float* dec_w  = (const float*)d_in[10];
  const float* dec_b  = (const float*)d_in[11];
  float* out = (float*)d_out;
  char*  ws  = (char*)d_ws;

  ushort_t* s0   = (ushort_t*)(ws + OB_S0);
  ushort_t* s1   = (ushort_t*)(ws + OB_S1);
  float*    part = (float*)(ws + OB_PART);

  (void)hipFuncSetAttribute((const void*)step_kernel,
                            hipFuncAttributeMaxDynamicSharedMemorySize, DYN_LDS);

  prep_kernel<<<309, 256, 0, stream>>>(up1_w, up2_w, tau_w, cb, stem_w, stem_b, ws);
  stem_kernel<<<1024, 256, 0, stream>>>(x, ws, s0);
  for (int s = 0; s < NSTEPS; ++s) {
    const ushort_t* in  = (s & 1) ? s1 : s0;
    ushort_t*       o   = (s & 1) ? s0 : s1;
    step_kernel<<<256, 1024, DYN_LDS, stream>>>(in, o, ws, up1_b, up2_b, tau_b,
                                                part + s * 8192);
  }
  dec_kernel<<<1024, 256, 0, stream>>>(s1, dec_w, dec_b, part, out);
}

// Round 10
// 358.497 us; speedup vs baseline: 3.0221x; 3.0221x over previous
//
#include <hip/hip_runtime.h>
#include <hip/hip_bf16.h>
#include <math.h>

typedef unsigned short ushort_t;
typedef __attribute__((ext_vector_type(8))) short short8;
typedef __attribute__((ext_vector_type(4))) float f32x4;
typedef __attribute__((ext_vector_type(4))) int int4v;
#define MFMA __builtin_amdgcn_mfma_f32_16x16x32_bf16

#define NPOS 262144
#define NSTEPS 5

// workspace byte offsets (guard page before state0 for wloc=-1 halo loads)
#define OB_S0   4096u
#define OB_S1   (OB_S0 + 33554432u)
#define OB_STG  (OB_S1 + 33554432u)       // 157696 B staged region: [w1f|w2f|wtf|cbf|nh]
#define STG_W2  73728u
#define STG_WT  81920u
#define STG_CB  90112u
#define STG_NH  155648u
#define STG_SZ  157696u
#define OB_SWT  (OB_STG + STG_SZ)         // f32 [9][64] stem weights (permuted slots)
#define OB_SBP  (OB_SWT + 2304u)          // f32 [64] stem bias (permuted)
#define OB_PART (OB_SBP + 256u)           // f32 [5][4096] per-wave partials
#define DYN_LDS 157696u
// LESSONS (R5-R9, unified VGPR/AGPR file): 1024-thr blocks force 4 waves/SIMD ->
// 128 total regs split 64 arch + 64 acc; every body tried (pf=4 and pf=2) overflows
// the 64-arch half -> 160-270 MB/dispatch scratch spill. 512-thr pf=4 (R4) is the
// proven clean config: 120 arch + ~64 acc, zero spill, 8 waves/CU (25% ceiling).
// Occupancy lever is exhausted; this round consolidates R4 + barrier/VALU trims.

// physical slot p = 32s + 8kg + 4u + r  ->  logical channel 32s + 16u + 4kg + r
static __device__ __forceinline__ int permP(int p) {
  return (p & 0x23) | ((p >> 1) & 0x0c) | ((p & 0x4) << 2);
}
static __device__ __forceinline__ ushort_t f2bf(float f) {
  __hip_bfloat16 h = __float2bfloat16(f);
  return *reinterpret_cast<ushort_t*>(&h);
}
static __device__ __forceinline__ float bf2f(ushort_t h) {
  return __uint_as_float(((unsigned)h) << 16);
}

// ---------------- prep: fragment-major bf16 weights/codebook + stem tables ----------------
__global__ void prep_kernel(const float* __restrict__ up1_w, const float* __restrict__ up2_w,
                            const float* __restrict__ tau_w, const float* __restrict__ cb,
                            const float* __restrict__ stem_w, const float* __restrict__ stem_b,
                            char* __restrict__ ws) {
  int id = blockIdx.x * 256 + threadIdx.x;
  ushort_t* stg = (ushort_t*)(ws + OB_STG);
  if (id < 36864) {                       // w1f: [tap][s][f][lane][j]
    int j = id & 7, lane = (id >> 3) & 63, f = (id >> 9) & 3, s = (id >> 11) & 1, tap = id >> 12;
    int col = lane & 15, kg = lane >> 4;
    stg[id] = f2bf(up1_w[((16 * f + col) * 64 + permP(32 * s + 8 * kg + j)) * 9 + tap]);
  } else if (id < 40960) {                // w2f: [s][f][lane][j]
    int jj = id - 36864;
    int j = jj & 7, lane = (jj >> 3) & 63, f = (jj >> 9) & 3, s = (jj >> 11) & 1;
    int col = lane & 15, kg = lane >> 4;
    stg[id] = f2bf(up2_w[(16 * f + col) * 64 + permP(32 * s + 8 * kg + j)]);
  } else if (id < 45056) {                // wtf
    int jj = id - 40960;
    int j = jj & 7, lane = (jj >> 3) & 63, f = (jj >> 9) & 3, s = (jj >> 11) & 1;
    int col = lane & 15, kg = lane >> 4;
    stg[id] = f2bf(tau_w[(16 * f + col) * 64 + permP(32 * s + 8 * kg + j)]);
  } else if (id < 77824) {                // cbf: [cf][s][lane][j]
    int jj = id - 45056;
    int j = jj & 7, lane = (jj >> 3) & 63, s = (jj >> 9) & 1, cf = jj >> 10;
    int col = lane & 15, kg = lane >> 4;
    stg[id] = f2bf(cb[(16 * cf + col) * 64 + permP(32 * s + 8 * kg + j)]);
  } else if (id < 78336) {                // nh = -0.5*|c|^2
    int k = id - 77824;
    float s = 0.f;
    for (int c = 0; c < 64; ++c) { float v = cb[k * 64 + c]; s += v * v; }
    ((float*)(ws + OB_STG + STG_NH))[k] = -0.5f * s;
  } else if (id < 78912) {                // stem weights [tap][slot]
    int jj = id - 78336; int tap = jj >> 6, slot = jj & 63;
    ((float*)(ws + OB_SWT))[jj] = stem_w[permP(slot) * 9 + tap];
  } else if (id < 78976) {                // stem bias [slot]
    int slot = id - 78912;
    ((float*)(ws + OB_SBP))[slot] = stem_b[permP(slot)];
  }
}

// ---------------- stem: conv3x3 1->64 + relu, thread-per-position ----------------
__global__ __launch_bounds__(256) void stem_kernel(const float* __restrict__ x,
      const char* __restrict__ wsro, ushort_t* __restrict__ state) {
  const float* swt = (const float*)(wsro + OB_SWT);
  const float* sbp = (const float*)(wsro + OB_SBP);
  int pos = blockIdx.x * 256 + threadIdx.x;
  int b = pos >> 14, hw = pos & 16383, h = hw >> 7, w = hw & 127;
  const float* xb = x + b * 16384;
  float xv[9];
  #pragma unroll
  for (int ky = 0; ky < 3; ++ky) {
    #pragma unroll
    for (int kx = 0; kx < 3; ++kx) {
      int hh = h + ky - 1, ww = w + kx - 1;
      bool ok = (hh >= 0) && (hh < 128) && (ww >= 0) && (ww < 128);
      xv[ky * 3 + kx] = ok ? xb[hh * 128 + ww] : 0.f;
    }
  }
  float acc[64];
  #pragma unroll
  for (int i = 0; i < 64; ++i) acc[i] = sbp[i];
  #pragma unroll
  for (int tap = 0; tap < 9; ++tap) {
    float xt = xv[tap];
    #pragma unroll
    for (int g = 0; g < 16; ++g) {
      f32x4 w4 = *(const f32x4*)(swt + tap * 64 + g * 4);
      #pragma unroll
      for (int j = 0; j < 4; ++j) acc[g * 4 + j] += xt * w4[j];
    }
  }
  ushort_t* op = state + (size_t)pos * 64;
  #pragma unroll
  for (int sg = 0; sg < 8; ++sg) {
    short8 o;
    #pragma unroll
    for (int j = 0; j < 8; ++j) o[j] = (short)f2bf(fmaxf(acc[sg * 8 + j], 0.f));
    *(short8*)(op + sg * 8) = o;
  }
}

// ---------------- fused step: LDS-resident weights, 512 thr, 2 work-units (R4 envelope) ----------------
// Block = 8 waves. Work-unit = 4 image rows (512 pos); wave owns 64 pos (4 pf).
__global__ __launch_bounds__(512, 2) void step_kernel(const ushort_t* __restrict__ sin,
      ushort_t* __restrict__ sout, const char* __restrict__ wsro,
      const float* __restrict__ up1_b, const float* __restrict__ up2_b,
      const float* __restrict__ tau_b, float* __restrict__ partials) {
  extern __shared__ char smem[];
  int t = threadIdx.x, lane = t & 63, wv = t >> 6;
  int col = lane & 15, kg = lane >> 4;

  // stage all weights/codebook into LDS (linear copy, conflict-free)
  const char* src = wsro + OB_STG;
  #pragma unroll
  for (int it = 0; it < 20; ++it) {
    int c = it * 512 + t;
    if (c < 9856) *(int4v*)(smem + c * 16) = *(const int4v*)(src + c * 16);
  }
  __syncthreads();

  for (int wi = 0; wi < 2; ++wi) {
    int wu = blockIdx.x + wi * 256;
    int lb = ((wu & 7) << 6) + (wu >> 3);     // XCD-chunked: XCD x owns images 2x,2x+1
    int b = lb >> 5;
    int row = (lb & 31) * 4 + (wv >> 1);
    int wseg = (wv & 1) * 64;
    const ushort_t* imgbase = sin + (size_t)b * 1048576u;

    // ---- up1: D = W1 . state^T (m=co, n=pos), A-frags from LDS ----
    f32x4 acc1[4][4] = {};                    // [pf][f]
    #pragma unroll
    for (int ky = 0; ky < 3; ++ky) {
      int h2 = row + ky - 1;
      if (h2 < 0 || h2 > 127) continue;       // wave-uniform
      const ushort_t* rptr = imgbase + h2 * 8192;
      #pragma unroll
      for (int kx = 0; kx < 3; ++kx) {
        short8 sbf[4][2];
        #pragma unroll
        for (int pf = 0; pf < 4; ++pf) {
          int wloc = wseg + 16 * pf + col + kx - 1;
          const ushort_t* pp = rptr + wloc * 64 + 8 * kg;
          sbf[pf][0] = *(const short8*)(pp);
          sbf[pf][1] = *(const short8*)(pp + 32);
          if ((kx == 0 && pf == 0) || (kx == 2 && pf == 3)) {
            if ((unsigned)wloc >= 128u) {
              short8 z8 = {};
              sbf[pf][0] = z8; sbf[pf][1] = z8;
            }
          }
        }
        int tap = ky * 3 + kx;
        #pragma unroll
        for (int s = 0; s < 2; ++s) {
          #pragma unroll
          for (int f = 0; f < 4; ++f) {
            short8 a = *(const short8*)(smem + ((tap * 2 + s) * 4 + f) * 1024 + lane * 16);
            #pragma unroll
            for (int pf = 0; pf < 4; ++pf)
              acc1[pf][f] = MFMA(a, sbf[pf][s], acc1[pf][f], 0, 0, 0);
          }
        }
      }
    }

    // ---- hidden = relu(D1+b1) packed to B-frag layout (slot identity) ----
    f32x4 b1v[4];
    #pragma unroll
    for (int f = 0; f < 4; ++f) b1v[f] = *(const f32x4*)(up1_b + 16 * f + 4 * kg);
    short8 hb[4][2];
    #pragma unroll
    for (int pf = 0; pf < 4; ++pf) {
      #pragma unroll
      for (int s = 0; s < 2; ++s) {
        short8 v;
        #pragma unroll
        for (int u = 0; u < 2; ++u) {
          int f = 2 * s + u;
          #pragma unroll
          for (int r = 0; r < 4; ++r)
            v[4 * u + r] = (short)f2bf(fmaxf(acc1[pf][f][r] + b1v[f][r], 0.f));
        }
        hb[pf][s] = v;
      }
    }

    // ---- up2/tau + gated z, pack zhat (weights from LDS) ----
    short8 zb[4][2];
    #pragma unroll
    for (int pf = 0; pf < 4; ++pf) {
      int wloc = wseg + 16 * pf + col;
      const ushort_t* cp = imgbase + row * 8192 + wloc * 64 + 8 * kg;
      short8 c0 = *(const short8*)(cp);
      short8 c1 = *(const short8*)(cp + 32);
      f32x4 d2[4] = {}, dt[4] = {};
      #pragma unroll
      for (int s = 0; s < 2; ++s) {
        short8 cs = s ? c1 : c0;
        #pragma unroll
        for (int f = 0; f < 4; ++f) {
          short8 wa2 = *(const short8*)(smem + STG_W2 + (s * 4 + f) * 1024 + lane * 16);
          short8 wat = *(const short8*)(smem + STG_WT + (s * 4 + f) * 1024 + lane * 16);
          d2[f] = MFMA(wa2, hb[pf][s], d2[f], 0, 0, 0);
          dt[f] = MFMA(wat, cs, dt[f], 0, 0, 0);
        }
      }
      #pragma unroll
      for (int s = 0; s < 2; ++s) {
        short8 cs = s ? c1 : c0;
        short8 zv;
        #pragma unroll
        for (int u = 0; u < 2; ++u) {
          int f = 2 * s + u;
          f32x4 b2 = *(const f32x4*)(up2_b + 16 * f + 4 * kg);
          f32x4 bt = *(const f32x4*)(tau_b + 16 * f + 4 * kg);
          #pragma unroll
          for (int r = 0; r < 4; ++r) {
            float sv = bf2f((ushort_t)cs[4 * u + r]);
            float xg = dt[f][r] + bt[r];
            float beta = __builtin_amdgcn_rcpf(1.f + __expf(-xg));
            float z = beta * sv + (1.f - beta) * (d2[f][r] + b2[r]);
            zv[4 * u + r] = (short)f2bf(z);
          }
        }
        zb[pf][s] = zv;
      }
    }

    // ---- VQ: argmax (z.c - |c|^2/2), codebook frags from LDS ----
    float bd[4] = {-3.0e38f, -3.0e38f, -3.0e38f, -3.0e38f};
    int bki[4] = {0, 0, 0, 0};
    #pragma unroll 2
    for (int cf = 0; cf < 32; ++cf) {
      short8 a0 = *(const short8*)(smem + STG_CB + (cf * 2 + 0) * 1024 + lane * 16);
      short8 a1 = *(const short8*)(smem + STG_CB + (cf * 2 + 1) * 1024 + lane * 16);
      f32x4 cinit = *(const f32x4*)(smem + STG_NH + (16 * cf + 4 * kg) * 4);
      #pragma unroll
      for (int pf = 0; pf < 4; ++pf) {
        f32x4 acc = cinit;
        acc = MFMA(a0, zb[pf][0], acc, 0, 0, 0);
        acc = MFMA(a1, zb[pf][1], acc, 0, 0, 0);
        #pragma unroll
        for (int r = 0; r < 4; ++r) {
          int code = 16 * cf + 4 * kg + r;
          if (acc[r] > bd[pf]) { bd[pf] = acc[r]; bki[pf] = code; }
        }
      }
    }

    // ---- cross-kg argmax, z_q gather from LDS codebook, store, loss ----
    // loss per position = |z|^2 - 2*bd  (bd = max score = z.c - |c|^2/2)
    float ls = 0.f;
    ushort_t* outbase = sout + (size_t)b * 1048576u + row * 8192;
    #pragma unroll
    for (int pf = 0; pf < 4; ++pf) {
      float d = bd[pf]; int k = bki[pf];
      #pragma unroll
      for (int off = 16; off <= 32; off <<= 1) {
        float od = __shfl_xor(d, off);
        int   ok = __shfl_xor(k, off);
        if (od > d || (od == d && ok < k)) { d = od; k = ok; }
      }
      int cbase = STG_CB + ((k >> 4) * 2) * 1024 + (16 * kg + (k & 15)) * 16;
      short8 q0 = *(const short8*)(smem + cbase);
      short8 q1 = *(const short8*)(smem + cbase + 1024);
      ushort_t* op = outbase + (wseg + 16 * pf + col) * 64 + 8 * kg;
      *(short8*)(op) = q0;
      *(short8*)(op + 32) = q1;
      float zn = 0.f;
      #pragma unroll
      for (int s = 0; s < 2; ++s) {
        short8 zv = zb[pf][s];
        #pragma unroll
        for (int j = 0; j < 8; ++j) {
          float v = bf2f((ushort_t)zv[j]);
          zn += v * v;
        }
      }
      zn += __shfl_xor(zn, 16);
      zn += __shfl_xor(zn, 32);
      if (kg == 0) ls += zn - 2.f * d;
    }
    #pragma unroll
    for (int off = 1; off < 64; off <<= 1) ls += __shfl_xor(ls, off);
    if (lane == 0) partials[wu * 8 + wv] = ls;   // per-wave partial, no LDS/barrier
  }
}

// ---------------- dec: 1x1 64->1 + sigmoid, coalesced; block 0 reduces loss ----------------
__global__ __launch_bounds__(256) void dec_kernel(const ushort_t* __restrict__ state,
      const float* __restrict__ dec_w, const float* __restrict__ dec_b,
      const float* __restrict__ part, float* __restrict__ out) {
  __shared__ float wsm[64];
  __shared__ float rs[256];
  int t = threadIdx.x;
  if (t < 64) wsm[t] = dec_w[permP(t)];
  __syncthreads();
  int wv = t >> 6, lane = t & 63;
  int pl = lane >> 3, sc = lane & 7;
  float b0 = dec_b[0];
  int base0 = blockIdx.x * 256;
  #pragma unroll
  for (int it = 0; it < 8; ++it) {
    int pos = base0 + it * 32 + wv * 8 + pl;
    short8 v = *(const short8*)(state + (size_t)pos * 64 + sc * 8);
    float d = 0.f;
    #pragma unroll
    for (int j = 0; j < 8; ++j) d += bf2f((ushort_t)v[j]) * wsm[sc * 8 + j];
    d += __shfl_xor(d, 1); d += __shfl_xor(d, 2); d += __shfl_xor(d, 4);
    if (sc == 0) out[pos] = __builtin_amdgcn_rcpf(1.f + __expf(-(d + b0)));
  }
  if (blockIdx.x == 0) {
    float v = 0.f;
    for (int i = t; i < 20480; i += 256) v += part[i];
    rs[t] = v;
    __syncthreads();
    for (int w = 128; w >= 1; w >>= 1) {
      if (t < w) rs[t] += rs[t + w];
      __syncthreads();
    }
    if (t == 0) out[NPOS] = rs[0] * 1.25f / (16777216.f * 5.f);
  }
}

extern "C" void kernel_launch(void* const* d_in, const int* in_sizes, int n_in,
                              void* d_out, int out_size, void* d_ws, size_t ws_size,
                              hipStream_t stream) {
  (void)in_sizes; (void)n_in; (void)out_size; (void)ws_size;
  const float* x      = (const float*)d_in[0];
  const float* stem_w = (const float*)d_in[1];
  const float* stem_b = (const float*)d_in[2];
  const float* up1_w  = (const float*)d_in[3];
  const float* up1_b  = (const float*)d_in[4];
  const float* up2_w  = (const float*)d_in[5];
  const float* up2_b  = (const float*)d_in[6];
  const float* tau_w  = (const float*)d_in[7];
  const float* tau_b  = (const float*)d_in[8];
  const float* cb     = (const float*)d_in[9];
  const float* dec_w  = (const float*)d_in[10];
  const float* dec_b  = (const float*)d_in[11];
  float* out = (float*)d_out;
  char*  ws  = (char*)d_ws;

  ushort_t* s0   = (ushort_t*)(ws + OB_S0);
  ushort_t* s1   = (ushort_t*)(ws + OB_S1);
  float*    part = (float*)(ws + OB_PART);

  (void)hipFuncSetAttribute((const void*)step_kernel,
                            hipFuncAttributeMaxDynamicSharedMemorySize, DYN_LDS);

  prep_kernel<<<309, 256, 0, stream>>>(up1_w, up2_w, tau_w, cb, stem_w, stem_b, ws);
  stem_kernel<<<1024, 256, 0, stream>>>(x, ws, s0);
  for (int s = 0; s < NSTEPS; ++s) {
    const ushort_t* in  = (s & 1) ? s1 : s0;
    ushort_t*       o   = (s & 1) ? s0 : s1;
    step_kernel<<<256, 512, DYN_LDS, stream>>>(in, o, ws, up1_b, up2_b, tau_b,
                                               part + s * 4096);
  }
  dec_kernel<<<1024, 256, 0, stream>>>(s1, dec_w, dec_b, part, out);
}